// Round 10
// baseline (222.238 us; speedup 1.0000x reference)
//
#include <hip/hip_runtime.h>

// B=2, NQ=S=2048, D=1024, H=16, HD=64, OUT=1024.
// prep: W* -> transposed bf16 only (Wq pre-scaled log2e/8).
// fused QKV GEMM: A fp32 reg-staged, B bf16 via gll16; BK=64 core; XCD-coop
//   mapping (r7-proven). z=2 writes V transposed with indicator folded in.
// flash split-K=4 (2048 blocks = 8/CU, 32 waves/CU, balanced 8-tile splits;
//   r8 body byte-identical otherwise -- r9's V-dereg REVERTED, failed refcheck):
//   St=K@Q^T, no-max exp2 softmax, P in registers (cvt_pk + permlane swaps),
//   16 KB LDS (K | V, Q prologue overlaid). 4th split buffer lives in d_out
//   (free until gemm_out, stream-ordered).
// combine: ctx = sum(c_s*l_s)/sum(l_s) over 4 splits
// out = ctx @ WoT (fp32): 64x64 tiles, 1024 blocks, XCD-coop, BK=64 core.

typedef float f32x4 __attribute__((ext_vector_type(4)));
typedef __bf16 bf16x8 __attribute__((ext_vector_type(8)));
typedef __bf16 bf16x4 __attribute__((ext_vector_type(4)));

#define DEVINL __device__ __forceinline__

DEVINL void gll16(const void* g, void* l) {
  __builtin_amdgcn_global_load_lds((const __attribute__((address_space(1))) void*)g,
                                   (__attribute__((address_space(3))) void*)l, 16, 0, 0);
}
DEVINL bf16x8 ldfrag(const void* p) { return __builtin_bit_cast(bf16x8, *(const int4*)p); }
DEVINL f32x4 mfma16(bf16x8 a, bf16x8 b, f32x4 c) {
  return __builtin_amdgcn_mfma_f32_16x16x32_bf16(a, b, c, 0, 0, 0);
}
// pack two f32 -> one u32 of 2 bf16 (lo = a, hi = b); compiler emits v_cvt_pk
DEVINL unsigned cvtpk(float a, float b) {
  union {
    __bf16 h[2];
    unsigned u;
  } r;
  r.h[0] = (__bf16)a;
  r.h[1] = (__bf16)b;
  return r.u;
}
DEVINL void swap32(unsigned& a, unsigned& b) {
  asm("v_permlane32_swap_b32 %0, %1" : "+v"(a), "+v"(b));
}
DEVINL void swap16(unsigned& a, unsigned& b) {
  asm("v_permlane16_swap_b32 %0, %1" : "+v"(a), "+v"(b));
}

// ---------------------------------------------------------------- prep (wtrans only)
// 32x32 transpose tiles of Wq/Wk/Wv/Wo (1024 blocks each, grid 4096)
__global__ __launch_bounds__(256) void prep_k(
    const float* __restrict__ Wq, const float* __restrict__ Wk,
    const float* __restrict__ Wv, const float* __restrict__ Wo,
    __bf16* __restrict__ o0, __bf16* __restrict__ o1, __bf16* __restrict__ o2,
    __bf16* __restrict__ o3) {
  __shared__ float tl[32][33];
  const int wid = blockIdx.x;
  const int t = threadIdx.x;
  int z = wid >> 10, x = wid & 31, y = (wid >> 5) & 31;
  const float* W = z == 0 ? Wq : z == 1 ? Wk : z == 2 ? Wv : Wo;
  __bf16* o = z == 0 ? o0 : z == 1 ? o1 : z == 2 ? o2 : o3;
  float scale = z == 0 ? 0.125f * 1.44269504f : 1.0f;
  int c0 = x * 32, r0 = y * 32;
  int tx = t & 31, ty = t >> 5;
#pragma unroll
  for (int rr = 0; rr < 32; rr += 8)
    tl[rr + ty][tx] = W[(size_t)(r0 + rr + ty) * 1024 + c0 + tx];
  __syncthreads();
#pragma unroll
  for (int cc = 0; cc < 32; cc += 8)
    o[(size_t)(c0 + cc + ty) * 1024 + r0 + tx] = (__bf16)(tl[tx][cc + ty] * scale);
}

// ---------------------------------------------------------------- GEMM core (BK=64)
// C tile (MT*32 x NT*32) = A[M][K] @ Bt[N][K]^T ; BK=64, 256 thr (4 waves as
// 2x2), single LDS buffer, two barriers per K-iter; 16 iters at K=1024. LDS rows
// 128 B, chunk swizzle ch^(row&7). F32A: A is fp32, reg-staged with cvt to the
// SAME swizzled LDS layout (reader contract unchanged); else A bf16 via gll16.
template <int MT, int NT, bool F32A>
DEVINL void gemm_core(const __bf16* __restrict__ Ab, const float* __restrict__ Af,
                      const __bf16* __restrict__ Bt, int K, int m0, int n0, char* As,
                      char* Bs, f32x4 (&acc)[MT][NT], int t) {
  const int lane = t & 63, wv = t >> 6;
  const int li = lane & 15, g = lane >> 4;
  const int wr = wv >> 1, wc = wv & 1;
  for (int kt = 0; kt < K; kt += 64) {
    if (kt) __syncthreads();  // prev-iter LDS reads done before re-staging
    float4 fa[MT][2];
    if constexpr (F32A) {
#pragma unroll
      for (int p = 0; p < MT; ++p) {
        int off = p * 4096 + t * 16;
        int row = off >> 7, ch = (off >> 4) & 7;
        int gch = ch ^ (row & 7);
        const float* src = Af + (size_t)(m0 + row) * 1024 + kt + gch * 8;
        fa[p][0] = *(const float4*)src;
        fa[p][1] = *(const float4*)(src + 4);
      }
    } else {
#pragma unroll
      for (int p = 0; p < MT; ++p) {
        int off = p * 4096 + t * 16;
        int row = off >> 7, ch = (off >> 4) & 7;
        int gch = ch ^ (row & 7);
        gll16((const char*)Ab + (size_t)(m0 + row) * (size_t)K * 2 + (size_t)kt * 2 +
                  gch * 16,
              As + off);
      }
    }
#pragma unroll
    for (int p = 0; p < NT; ++p) {
      int off = p * 4096 + t * 16;
      int row = off >> 7, ch = (off >> 4) & 7;
      int gch = ch ^ (row & 7);
      gll16((const char*)Bt + (size_t)(n0 + row) * (size_t)K * 2 + (size_t)kt * 2 +
                gch * 16,
            Bs + off);
    }
    if constexpr (F32A) {
#pragma unroll
      for (int p = 0; p < MT; ++p) {
        int off = p * 4096 + t * 16;
        int4 w = {(int)cvtpk(fa[p][0].x, fa[p][0].y), (int)cvtpk(fa[p][0].z, fa[p][0].w),
                  (int)cvtpk(fa[p][1].x, fa[p][1].y),
                  (int)cvtpk(fa[p][1].z, fa[p][1].w)};
        *(int4*)(As + off) = w;
      }
    }
    __syncthreads();  // staging drained before fragment reads
#pragma unroll
    for (int ks = 0; ks < 2; ++ks) {
      bf16x8 af[MT], bfr[NT];
#pragma unroll
      for (int mt = 0; mt < MT; ++mt) {
        int row = wr * (MT * 16) + mt * 16 + li;
        int pc = (4 * ks + g) ^ (row & 7);
        af[mt] = ldfrag(As + row * 128 + pc * 16);
      }
#pragma unroll
      for (int nt = 0; nt < NT; ++nt) {
        int row = wc * (NT * 16) + nt * 16 + li;
        int pc = (4 * ks + g) ^ (row & 7);
        bfr[nt] = ldfrag(Bs + row * 128 + pc * 16);
      }
#pragma unroll
      for (int mt = 0; mt < MT; ++mt)
#pragma unroll
        for (int nt = 0; nt < NT; ++nt)
          acc[mt][nt] = mfma16(af[mt], bfr[nt], acc[mt][nt]);
    }
  }
}

// fused Q/K/V projections from fp32 inputs: grid (8, 32, 3); z=2 writes V
// transposed with the indicator folded in: Vt[n][s] = (v@WvT)[s][n] * ind[s].
// XCD-cooperative mapping: xcd = bid&7 owns m-panels [4*xcd, 4*xcd+4), n fastest
// within the XCD -> A-panel re-reads are same-XCD L2 hits (r7-proven).
__global__ __launch_bounds__(256) void gemm_qkv(
    const float* __restrict__ q, const float* __restrict__ k,
    const float* __restrict__ v, const __bf16* __restrict__ WqT,
    const __bf16* __restrict__ WkT, const __bf16* __restrict__ WvT,
    const float* __restrict__ ind, __bf16* __restrict__ Qp, __bf16* __restrict__ Kp,
    __bf16* __restrict__ Vtp) {
  __shared__ __align__(16) char As[16384];
  __shared__ __align__(16) char Bs[16384];
  const int z = blockIdx.z;
  const float* A = z == 0 ? q : z == 1 ? k : v;
  const __bf16* Bt = z == 0 ? WqT : z == 1 ? WkT : WvT;
  const int bid = blockIdx.x + (int)blockIdx.y * 8;  // 0..255
  const int xcd = bid & 7, idx = bid >> 3;
  const int m0 = (xcd * 4 + (idx >> 3)) * 128;  // bijective: 4 m-panels per XCD
  const int n0 = (idx & 7) * 128;               // n innermost within XCD
  f32x4 acc[4][4] = {};
  gemm_core<4, 4, true>(nullptr, A, Bt, 1024, m0, n0, As, Bs, acc, threadIdx.x);
  const int lane = threadIdx.x & 63, wv = threadIdx.x >> 6;
  const int li = lane & 15, g = lane >> 4;
  const int wr = wv >> 1, wc = wv & 1;
#pragma unroll
  for (int mt = 0; mt < 4; ++mt)
#pragma unroll
    for (int nt = 0; nt < 4; ++nt) {
      int m = m0 + wr * 64 + mt * 16 + g * 4;
      int n = n0 + wc * 64 + nt * 16 + li;
      if (z < 2) {
        __bf16* Cb = z ? Kp : Qp;
#pragma unroll
        for (int r = 0; r < 4; ++r)
          Cb[(size_t)(m + r) * 1024 + n] = (__bf16)acc[mt][nt][r];
      } else {
        float4 i4 = *(const float4*)(ind + m);  // m is the flat sequence index
        bf16x4 o = {(__bf16)(acc[mt][nt][0] * i4.x), (__bf16)(acc[mt][nt][1] * i4.y),
                    (__bf16)(acc[mt][nt][2] * i4.z), (__bf16)(acc[mt][nt][3] * i4.w)};
        *(bf16x4*)(Vtp + (size_t)n * 4096 + m) = o;
      }
    }
}

// out = ctx @ WoT, fp32; 64x64 tiles, grid (16, 64) = 1024 blocks = 4/CU,
// XCD-coop (xcd owns 8 contiguous 64-row m-panels, n innermost).
__global__ __launch_bounds__(256) void gemm_out(const __bf16* __restrict__ ctx,
                                                const __bf16* __restrict__ WoT,
                                                float* __restrict__ out) {
  __shared__ __align__(16) char As[8192];
  __shared__ __align__(16) char Bs[8192];
  const int bid = blockIdx.x + (int)blockIdx.y * 16;  // 0..1023
  const int xcd = bid & 7, idx = bid >> 3;            // idx 0..127
  const int m0 = (xcd * 8 + (idx >> 4)) * 64;  // bijective: 8 m-panels per XCD
  const int n0 = (idx & 15) * 64;              // n innermost within XCD
  f32x4 acc[2][2] = {};
  gemm_core<2, 2, false>(ctx, nullptr, WoT, 1024, m0, n0, As, Bs, acc, threadIdx.x);
  const int lane = threadIdx.x & 63, wv = threadIdx.x >> 6;
  const int li = lane & 15, g = lane >> 4;
  const int wr = wv >> 1, wc = wv & 1;
#pragma unroll
  for (int mt = 0; mt < 2; ++mt)
#pragma unroll
    for (int nt = 0; nt < 2; ++nt) {
      int m = m0 + wr * 32 + mt * 16 + g * 4;
      int n = n0 + wc * 32 + nt * 16 + li;
#pragma unroll
      for (int r = 0; r < 4; ++r) out[(size_t)(m + r) * 1024 + n] = acc[mt][nt][r];
    }
}

// ---------------------------------------------------------------- flash attention
// split-K=4: grid 2048 = sp(4) x [b(2) x h(16) x qtile(16 of 128 rows)] ->
// 8 blocks/CU, 32 waves/CU, balanced 8-tile splits. 256 thr = 4 waves, 32
// q/wave. r1-proven body: 16 KB LDS (K | V, Q prologue overlaid), two barriers
// per tile, P in registers via cvt_pk + permlane swaps.
__global__ __launch_bounds__(256) void flash_k(
    const __bf16* __restrict__ Qp, const __bf16* __restrict__ Kp,
    const __bf16* __restrict__ Vt, __bf16* __restrict__ ctx0,
    __bf16* __restrict__ ctx1, __bf16* __restrict__ ctx2, __bf16* __restrict__ ctx3,
    float* __restrict__ pl) {
  __shared__ __align__(16) char smem[16384];
  char* kv = smem;  // K [0,8192) rows 64x128B | V [8192,16384); Q prologue overlays
  const int t = threadIdx.x;
  const int lane = t & 63, wv = t >> 6;
  const int li = lane & 15, g = lane >> 4;
  const int sp = blockIdx.x >> 9, rest = blockIdx.x & 511;
  const int qt = rest & 15, h = (rest >> 4) & 15, b = rest >> 8;
  const int kt0 = sp * 8, kt1 = sp * 8 + 8;
  const size_t qrow0 = (size_t)b * 2048 + (size_t)qt * 128;
  __bf16* ctx = sp == 0 ? ctx0 : (sp == 1 ? ctx1 : (sp == 2 ? ctx2 : ctx3));

  // prologue: stage Q [128 q][64 d] into kv region, pull frags to registers
#pragma unroll
  for (int p = 0; p < 4; ++p) {
    int off = p * 4096 + t * 16;
    int row = off >> 7, ch = (off >> 4) & 7;
    int gch = ch ^ (row & 7);
    gll16((const char*)Qp + ((qrow0 + row) * 1024 + h * 64) * 2 + gch * 16, smem + off);
  }
  __syncthreads();

  bf16x8 qf[2][2];
#pragma unroll
  for (int nt = 0; nt < 2; ++nt)
#pragma unroll
    for (int ks = 0; ks < 2; ++ks) {
      int row = wv * 32 + nt * 16 + li;
      int gch = (4 * ks + g) ^ (row & 7);
      qf[nt][ks] = ldfrag(smem + row * 128 + gch * 16);
    }

  f32x4 acc[4][2] = {};          // ctx^T [d = mtd*16+4g+r][q = nt*16+li]
  float lsum[2] = {0.0f, 0.0f};  // in-lane partial denominators

  for (int kt = kt0; kt < kt1; ++kt) {
    __syncthreads();  // prev-iter kv reads + (kt==first) Q/qf reads done
#pragma unroll
    for (int p = 0; p < 2; ++p) {
      int off = p * 4096 + t * 16;
      int row = off >> 7, ch = (off >> 4) & 7;
      int gch = ch ^ (row & 7);
      gll16((const char*)Kp +
                (((size_t)b * 2048 + kt * 64 + row) * 1024 + h * 64) * 2 + gch * 16,
            kv + off);
      gll16((const char*)Vt +
                ((size_t)(h * 64 + row) * 4096 + (size_t)b * 2048 + kt * 64) * 2 +
                gch * 16,
            kv + 8192 + off);
    }
    __syncthreads();  // staging drained

    // QK (mt-major, st transient) -> exp2 -> packed bf16 pairs in registers
    unsigned pk[4][2][2];  // [mt][nt][word]: w0 = keys gs*4+{0,1}, w1 = +{2,3}
#pragma unroll
    for (int mt = 0; mt < 4; ++mt) {
      f32x4 st0 = {}, st1 = {};
      int row = mt * 16 + li;
#pragma unroll
      for (int ks = 0; ks < 2; ++ks) {
        int gch = (4 * ks + g) ^ (row & 7);
        bf16x8 kf = ldfrag(kv + row * 128 + gch * 16);
        st0 = mfma16(kf, qf[0][ks], st0);
        st1 = mfma16(kf, qf[1][ks], st1);
      }
      float p0 = __builtin_amdgcn_exp2f(st0[0]);
      float p1 = __builtin_amdgcn_exp2f(st0[1]);
      float p2 = __builtin_amdgcn_exp2f(st0[2]);
      float p3 = __builtin_amdgcn_exp2f(st0[3]);
      lsum[0] += (p0 + p1) + (p2 + p3);
      pk[mt][0][0] = cvtpk(p0, p1);
      pk[mt][0][1] = cvtpk(p2, p3);
      p0 = __builtin_amdgcn_exp2f(st1[0]);
      p1 = __builtin_amdgcn_exp2f(st1[1]);
      p2 = __builtin_amdgcn_exp2f(st1[2]);
      p3 = __builtin_amdgcn_exp2f(st1[3]);
      lsum[1] += (p0 + p1) + (p2 + p3);
      pk[mt][1][0] = cvtpk(p0, p1);
      pk[mt][1][1] = cvtpk(p2, p3);
    }

    // in-register C-layout -> B-frag remap, then PV: acc += Vt_frag x P_frag
#pragma unroll
    for (int kc = 0; kc < 2; ++kc) {
      unsigned a00 = pk[2 * kc][0][0], b00 = pk[2 * kc + 1][0][0];
      unsigned a01 = pk[2 * kc][0][1], b01 = pk[2 * kc + 1][0][1];
      unsigned a10 = pk[2 * kc][1][0], b10 = pk[2 * kc + 1][1][0];
      unsigned a11 = pk[2 * kc][1][1], b11 = pk[2 * kc + 1][1][1];
      swap32(a00, b00);
      swap16(a00, b00);
      swap32(a01, b01);
      swap16(a01, b01);
      swap32(a10, b10);
      swap16(a10, b10);
      swap32(a11, b11);
      swap16(a11, b11);
      uint4 u0 = {a00, a01, b00, b01};  // words 0..3: keys kc*32+g*8+{0..7}, q=li
      uint4 u1 = {a10, a11, b10, b11};
      bf16x8 pf0 = __builtin_bit_cast(bf16x8, u0);
      bf16x8 pf1 = __builtin_bit_cast(bf16x8, u1);
#pragma unroll
      for (int mtd = 0; mtd < 4; ++mtd) {
        int row = mtd * 16 + li;
        int gch = (4 * kc + g) ^ (row & 7);
        bf16x8 vf = ldfrag(kv + 8192 + row * 128 + gch * 16);
        acc[mtd][0] = mfma16(vf, pf0, acc[mtd][0]);
        acc[mtd][1] = mfma16(vf, pf1, acc[mtd][1]);
      }
    }
  }

#pragma unroll
  for (int nt = 0; nt < 2; ++nt) {
    float l = lsum[nt];
    l += __shfl_xor(l, 16);
    l += __shfl_xor(l, 32);  // split-local denominator for q = nt*16+li
    float linv = 1.0f / l;
    size_t qrow = qrow0 + wv * 32 + nt * 16 + li;
    if (g == 0) pl[((size_t)sp * 4096 + qrow) * 16 + h] = l;
#pragma unroll
    for (int mtd = 0; mtd < 4; ++mtd) {
      bf16x4 o = {(__bf16)(acc[mtd][nt][0] * linv), (__bf16)(acc[mtd][nt][1] * linv),
                  (__bf16)(acc[mtd][nt][2] * linv), (__bf16)(acc[mtd][nt][3] * linv)};
      *(bf16x4*)(ctx + qrow * 1024 + h * 64 + mtd * 16 + g * 4) = o;
    }
  }
}

// combine splits: ctx = sum(c_s*l_s) / sum(l_s) over 4 splits; 8 elems/thread
__global__ __launch_bounds__(256) void combine_k(
    const __bf16* __restrict__ c0, const __bf16* __restrict__ c1,
    const __bf16* __restrict__ c2, const __bf16* __restrict__ c3,
    const float* __restrict__ pl, __bf16* __restrict__ ctx) {
  size_t e = ((size_t)blockIdx.x * 256 + threadIdx.x) * 8;
  int qrow = (int)(e >> 10), h = ((int)e & 1023) >> 6;
  float l0 = pl[(size_t)qrow * 16 + h];
  float l1 = pl[(size_t)(4096 + qrow) * 16 + h];
  float l2 = pl[(size_t)(8192 + qrow) * 16 + h];
  float l3 = pl[(size_t)(12288 + qrow) * 16 + h];
  float w = 1.0f / (l0 + l1 + l2 + l3);
  float w0 = l0 * w, w1 = l1 * w, w2 = l2 * w, w3 = l3 * w;
  bf16x8 a = *(const bf16x8*)(c0 + e);
  bf16x8 b = *(const bf16x8*)(c1 + e);
  bf16x8 c = *(const bf16x8*)(c2 + e);
  bf16x8 d = *(const bf16x8*)(c3 + e);
  bf16x8 o;
#pragma unroll
  for (int i = 0; i < 8; ++i)
    o[i] = (__bf16)((float)a[i] * w0 + (float)b[i] * w1 + (float)c[i] * w2 +
                    (float)d[i] * w3);
  *(bf16x8*)(ctx + e) = o;
}

// ---------------------------------------------------------------- launch
extern "C" void kernel_launch(void* const* d_in, const int* in_sizes, int n_in,
                              void* d_out, int out_size, void* d_ws, size_t ws_size,
                              hipStream_t stream) {
  const float* q = (const float*)d_in[0];
  const float* k = (const float*)d_in[1];
  const float* v = (const float*)d_in[2];
  const float* ind = (const float*)d_in[3];
  const float* Wq = (const float*)d_in[4];
  const float* Wk = (const float*)d_in[5];
  const float* Wv = (const float*)d_in[6];
  const float* Wo = (const float*)d_in[7];
  char* ws = (char*)d_ws;
  const size_t MB = 1024 * 1024;
  __bf16* WqT = (__bf16*)(ws + 24 * MB);
  __bf16* WkT = (__bf16*)(ws + 26 * MB);
  __bf16* WvT = (__bf16*)(ws + 28 * MB);
  __bf16* WoT = (__bf16*)(ws + 30 * MB);
  __bf16* Qp = (__bf16*)(ws + 32 * MB);
  __bf16* Kp = (__bf16*)(ws + 40 * MB);
  __bf16* Vtp = (__bf16*)(ws + 48 * MB);
  // 0-24 MB free for flash outputs; WqT/WkT/WvT dead after gemm_qkv
  __bf16* ctx0 = (__bf16*)(ws + 0);
  __bf16* ctx1 = (__bf16*)(ws + 8 * MB);
  __bf16* ctx2 = (__bf16*)(ws + 16 * MB);
  __bf16* ctx3 = (__bf16*)d_out;  // d_out (16 MB) is free until gemm_out writes it
  float* pl = (float*)(ws + 24 * MB);     // [4][4096][16] f32 = 1 MB (dead WqT)
  __bf16* ctx = (__bf16*)(ws + 48 * MB);  // over Vtp, dead once flash_k is done
  float* out = (float*)d_out;

  prep_k<<<dim3(4096), 256, 0, stream>>>(Wq, Wk, Wv, Wo, WqT, WkT, WvT, WoT);
  gemm_qkv<<<dim3(8, 32, 3), 256, 0, stream>>>(q, k, v, WqT, WkT, WvT, ind, Qp, Kp,
                                               Vtp);
  flash_k<<<dim3(2048), 256, 0, stream>>>(Qp, Kp, Vtp, ctx0, ctx1, ctx2, ctx3, pl);
  combine_k<<<dim3(2048), 256, 0, stream>>>(ctx0, ctx1, ctx2, ctx3, pl, ctx);
  gemm_out<<<dim3(16, 64), 256, 0, stream>>>(ctx, WoT, out);
}

// Round 11
// 217.357 us; speedup vs baseline: 1.0225x; 1.0225x over previous
//
#include <hip/hip_runtime.h>

// B=2, NQ=S=2048, D=1024, H=16, HD=64, OUT=1024.
// prep: W* -> transposed bf16 only (Wq pre-scaled log2e/8).
// fused QKV GEMM: A fp32 reg-staged, B bf16 via gll16; BK=64 core; XCD-coop
//   mapping (r7-proven). z=2 writes V transposed with indicator folded in.
// flash split-K=3 (1536 blocks, r8-proven body; sp=4 REVERTED, regressed r10):
//   St=K@Q^T, no-max exp2 softmax, P in registers (cvt_pk + permlane swaps),
//   16 KB LDS (K | V, Q prologue overlaid). NEW (isolated): s_setprio(1)
//   around the QK and PV MFMA clusters (T5; m191 regime: independent blocks
//   at staggered phases per CU).
// combine: ctx = (c0*l0+c1*l1+c2*l2)/(l0+l1+l2)
// out = ctx @ WoT (fp32): 64x64 tiles, 1024 blocks, XCD-coop, BK=64 core.

typedef float f32x4 __attribute__((ext_vector_type(4)));
typedef __bf16 bf16x8 __attribute__((ext_vector_type(8)));
typedef __bf16 bf16x4 __attribute__((ext_vector_type(4)));

#define DEVINL __device__ __forceinline__

DEVINL void gll16(const void* g, void* l) {
  __builtin_amdgcn_global_load_lds((const __attribute__((address_space(1))) void*)g,
                                   (__attribute__((address_space(3))) void*)l, 16, 0, 0);
}
DEVINL bf16x8 ldfrag(const void* p) { return __builtin_bit_cast(bf16x8, *(const int4*)p); }
DEVINL f32x4 mfma16(bf16x8 a, bf16x8 b, f32x4 c) {
  return __builtin_amdgcn_mfma_f32_16x16x32_bf16(a, b, c, 0, 0, 0);
}
// pack two f32 -> one u32 of 2 bf16 (lo = a, hi = b); compiler emits v_cvt_pk
DEVINL unsigned cvtpk(float a, float b) {
  union {
    __bf16 h[2];
    unsigned u;
  } r;
  r.h[0] = (__bf16)a;
  r.h[1] = (__bf16)b;
  return r.u;
}
DEVINL void swap32(unsigned& a, unsigned& b) {
  asm("v_permlane32_swap_b32 %0, %1" : "+v"(a), "+v"(b));
}
DEVINL void swap16(unsigned& a, unsigned& b) {
  asm("v_permlane16_swap_b32 %0, %1" : "+v"(a), "+v"(b));
}

// ---------------------------------------------------------------- prep (wtrans only)
// 32x32 transpose tiles of Wq/Wk/Wv/Wo (1024 blocks each, grid 4096)
__global__ __launch_bounds__(256) void prep_k(
    const float* __restrict__ Wq, const float* __restrict__ Wk,
    const float* __restrict__ Wv, const float* __restrict__ Wo,
    __bf16* __restrict__ o0, __bf16* __restrict__ o1, __bf16* __restrict__ o2,
    __bf16* __restrict__ o3) {
  __shared__ float tl[32][33];
  const int wid = blockIdx.x;
  const int t = threadIdx.x;
  int z = wid >> 10, x = wid & 31, y = (wid >> 5) & 31;
  const float* W = z == 0 ? Wq : z == 1 ? Wk : z == 2 ? Wv : Wo;
  __bf16* o = z == 0 ? o0 : z == 1 ? o1 : z == 2 ? o2 : o3;
  float scale = z == 0 ? 0.125f * 1.44269504f : 1.0f;
  int c0 = x * 32, r0 = y * 32;
  int tx = t & 31, ty = t >> 5;
#pragma unroll
  for (int rr = 0; rr < 32; rr += 8)
    tl[rr + ty][tx] = W[(size_t)(r0 + rr + ty) * 1024 + c0 + tx];
  __syncthreads();
#pragma unroll
  for (int cc = 0; cc < 32; cc += 8)
    o[(size_t)(c0 + cc + ty) * 1024 + r0 + tx] = (__bf16)(tl[tx][cc + ty] * scale);
}

// ---------------------------------------------------------------- GEMM core (BK=64)
// C tile (MT*32 x NT*32) = A[M][K] @ Bt[N][K]^T ; BK=64, 256 thr (4 waves as
// 2x2), single LDS buffer, two barriers per K-iter; 16 iters at K=1024. LDS rows
// 128 B, chunk swizzle ch^(row&7). F32A: A is fp32, reg-staged with cvt to the
// SAME swizzled LDS layout (reader contract unchanged); else A bf16 via gll16.
template <int MT, int NT, bool F32A>
DEVINL void gemm_core(const __bf16* __restrict__ Ab, const float* __restrict__ Af,
                      const __bf16* __restrict__ Bt, int K, int m0, int n0, char* As,
                      char* Bs, f32x4 (&acc)[MT][NT], int t) {
  const int lane = t & 63, wv = t >> 6;
  const int li = lane & 15, g = lane >> 4;
  const int wr = wv >> 1, wc = wv & 1;
  for (int kt = 0; kt < K; kt += 64) {
    if (kt) __syncthreads();  // prev-iter LDS reads done before re-staging
    float4 fa[MT][2];
    if constexpr (F32A) {
#pragma unroll
      for (int p = 0; p < MT; ++p) {
        int off = p * 4096 + t * 16;
        int row = off >> 7, ch = (off >> 4) & 7;
        int gch = ch ^ (row & 7);
        const float* src = Af + (size_t)(m0 + row) * 1024 + kt + gch * 8;
        fa[p][0] = *(const float4*)src;
        fa[p][1] = *(const float4*)(src + 4);
      }
    } else {
#pragma unroll
      for (int p = 0; p < MT; ++p) {
        int off = p * 4096 + t * 16;
        int row = off >> 7, ch = (off >> 4) & 7;
        int gch = ch ^ (row & 7);
        gll16((const char*)Ab + (size_t)(m0 + row) * (size_t)K * 2 + (size_t)kt * 2 +
                  gch * 16,
              As + off);
      }
    }
#pragma unroll
    for (int p = 0; p < NT; ++p) {
      int off = p * 4096 + t * 16;
      int row = off >> 7, ch = (off >> 4) & 7;
      int gch = ch ^ (row & 7);
      gll16((const char*)Bt + (size_t)(n0 + row) * (size_t)K * 2 + (size_t)kt * 2 +
                gch * 16,
            Bs + off);
    }
    if constexpr (F32A) {
#pragma unroll
      for (int p = 0; p < MT; ++p) {
        int off = p * 4096 + t * 16;
        int4 w = {(int)cvtpk(fa[p][0].x, fa[p][0].y), (int)cvtpk(fa[p][0].z, fa[p][0].w),
                  (int)cvtpk(fa[p][1].x, fa[p][1].y),
                  (int)cvtpk(fa[p][1].z, fa[p][1].w)};
        *(int4*)(As + off) = w;
      }
    }
    __syncthreads();  // staging drained before fragment reads
#pragma unroll
    for (int ks = 0; ks < 2; ++ks) {
      bf16x8 af[MT], bfr[NT];
#pragma unroll
      for (int mt = 0; mt < MT; ++mt) {
        int row = wr * (MT * 16) + mt * 16 + li;
        int pc = (4 * ks + g) ^ (row & 7);
        af[mt] = ldfrag(As + row * 128 + pc * 16);
      }
#pragma unroll
      for (int nt = 0; nt < NT; ++nt) {
        int row = wc * (NT * 16) + nt * 16 + li;
        int pc = (4 * ks + g) ^ (row & 7);
        bfr[nt] = ldfrag(Bs + row * 128 + pc * 16);
      }
#pragma unroll
      for (int mt = 0; mt < MT; ++mt)
#pragma unroll
        for (int nt = 0; nt < NT; ++nt)
          acc[mt][nt] = mfma16(af[mt], bfr[nt], acc[mt][nt]);
    }
  }
}

// fused Q/K/V projections from fp32 inputs: grid (8, 32, 3); z=2 writes V
// transposed with the indicator folded in: Vt[n][s] = (v@WvT)[s][n] * ind[s].
// XCD-cooperative mapping: xcd = bid&7 owns m-panels [4*xcd, 4*xcd+4), n fastest
// within the XCD -> A-panel re-reads are same-XCD L2 hits (r7-proven).
__global__ __launch_bounds__(256) void gemm_qkv(
    const float* __restrict__ q, const float* __restrict__ k,
    const float* __restrict__ v, const __bf16* __restrict__ WqT,
    const __bf16* __restrict__ WkT, const __bf16* __restrict__ WvT,
    const float* __restrict__ ind, __bf16* __restrict__ Qp, __bf16* __restrict__ Kp,
    __bf16* __restrict__ Vtp) {
  __shared__ __align__(16) char As[16384];
  __shared__ __align__(16) char Bs[16384];
  const int z = blockIdx.z;
  const float* A = z == 0 ? q : z == 1 ? k : v;
  const __bf16* Bt = z == 0 ? WqT : z == 1 ? WkT : WvT;
  const int bid = blockIdx.x + (int)blockIdx.y * 8;  // 0..255
  const int xcd = bid & 7, idx = bid >> 3;
  const int m0 = (xcd * 4 + (idx >> 3)) * 128;  // bijective: 4 m-panels per XCD
  const int n0 = (idx & 7) * 128;               // n innermost within XCD
  f32x4 acc[4][4] = {};
  gemm_core<4, 4, true>(nullptr, A, Bt, 1024, m0, n0, As, Bs, acc, threadIdx.x);
  const int lane = threadIdx.x & 63, wv = threadIdx.x >> 6;
  const int li = lane & 15, g = lane >> 4;
  const int wr = wv >> 1, wc = wv & 1;
#pragma unroll
  for (int mt = 0; mt < 4; ++mt)
#pragma unroll
    for (int nt = 0; nt < 4; ++nt) {
      int m = m0 + wr * 64 + mt * 16 + g * 4;
      int n = n0 + wc * 64 + nt * 16 + li;
      if (z < 2) {
        __bf16* Cb = z ? Kp : Qp;
#pragma unroll
        for (int r = 0; r < 4; ++r)
          Cb[(size_t)(m + r) * 1024 + n] = (__bf16)acc[mt][nt][r];
      } else {
        float4 i4 = *(const float4*)(ind + m);  // m is the flat sequence index
        bf16x4 o = {(__bf16)(acc[mt][nt][0] * i4.x), (__bf16)(acc[mt][nt][1] * i4.y),
                    (__bf16)(acc[mt][nt][2] * i4.z), (__bf16)(acc[mt][nt][3] * i4.w)};
        *(bf16x4*)(Vtp + (size_t)n * 4096 + m) = o;
      }
    }
}

// out = ctx @ WoT, fp32; 64x64 tiles, grid (16, 64) = 1024 blocks = 4/CU,
// XCD-coop (xcd owns 8 contiguous 64-row m-panels, n innermost).
__global__ __launch_bounds__(256) void gemm_out(const __bf16* __restrict__ ctx,
                                                const __bf16* __restrict__ WoT,
                                                float* __restrict__ out) {
  __shared__ __align__(16) char As[8192];
  __shared__ __align__(16) char Bs[8192];
  const int bid = blockIdx.x + (int)blockIdx.y * 16;  // 0..1023
  const int xcd = bid & 7, idx = bid >> 3;            // idx 0..127
  const int m0 = (xcd * 8 + (idx >> 4)) * 64;  // bijective: 8 m-panels per XCD
  const int n0 = (idx & 15) * 64;              // n innermost within XCD
  f32x4 acc[2][2] = {};
  gemm_core<2, 2, false>(ctx, nullptr, WoT, 1024, m0, n0, As, Bs, acc, threadIdx.x);
  const int lane = threadIdx.x & 63, wv = threadIdx.x >> 6;
  const int li = lane & 15, g = lane >> 4;
  const int wr = wv >> 1, wc = wv & 1;
#pragma unroll
  for (int mt = 0; mt < 2; ++mt)
#pragma unroll
    for (int nt = 0; nt < 2; ++nt) {
      int m = m0 + wr * 32 + mt * 16 + g * 4;
      int n = n0 + wc * 32 + nt * 16 + li;
#pragma unroll
      for (int r = 0; r < 4; ++r) out[(size_t)(m + r) * 1024 + n] = acc[mt][nt][r];
    }
}

// ---------------------------------------------------------------- flash attention
// split-K=3: grid 1536 = sp(3) x [b(2) x h(16) x qtile(16 of 128 rows)].
// 256 thr = 4 waves, 32 q/wave. r8-proven body: 16 KB LDS (K | V, Q prologue
// overlaid), two barriers per tile, P in registers via cvt_pk + permlane swaps.
// T5: setprio(1) around the QK and PV MFMA clusters (isolated this round).
__global__ __launch_bounds__(256) void flash_k(
    const __bf16* __restrict__ Qp, const __bf16* __restrict__ Kp,
    const __bf16* __restrict__ Vt, __bf16* __restrict__ ctx0,
    __bf16* __restrict__ ctx1, __bf16* __restrict__ ctx2, float* __restrict__ pl) {
  __shared__ __align__(16) char smem[16384];
  char* kv = smem;  // K [0,8192) rows 64x128B | V [8192,16384); Q prologue overlays
  const int t = threadIdx.x;
  const int lane = t & 63, wv = t >> 6;
  const int li = lane & 15, g = lane >> 4;
  const int sp = blockIdx.x >> 9, rest = blockIdx.x & 511;
  const int qt = rest & 15, h = (rest >> 4) & 15, b = rest >> 8;
  const int kt0 = (sp * 32) / 3, kt1 = (sp * 32 + 32) / 3;
  const size_t qrow0 = (size_t)b * 2048 + (size_t)qt * 128;
  __bf16* ctx = sp == 0 ? ctx0 : (sp == 1 ? ctx1 : ctx2);

  // prologue: stage Q [128 q][64 d] into kv region, pull frags to registers
#pragma unroll
  for (int p = 0; p < 4; ++p) {
    int off = p * 4096 + t * 16;
    int row = off >> 7, ch = (off >> 4) & 7;
    int gch = ch ^ (row & 7);
    gll16((const char*)Qp + ((qrow0 + row) * 1024 + h * 64) * 2 + gch * 16, smem + off);
  }
  __syncthreads();

  bf16x8 qf[2][2];
#pragma unroll
  for (int nt = 0; nt < 2; ++nt)
#pragma unroll
    for (int ks = 0; ks < 2; ++ks) {
      int row = wv * 32 + nt * 16 + li;
      int gch = (4 * ks + g) ^ (row & 7);
      qf[nt][ks] = ldfrag(smem + row * 128 + gch * 16);
    }

  f32x4 acc[4][2] = {};          // ctx^T [d = mtd*16+4g+r][q = nt*16+li]
  float lsum[2] = {0.0f, 0.0f};  // in-lane partial denominators

  for (int kt = kt0; kt < kt1; ++kt) {
    __syncthreads();  // prev-iter kv reads + (kt==first) Q/qf reads done
#pragma unroll
    for (int p = 0; p < 2; ++p) {
      int off = p * 4096 + t * 16;
      int row = off >> 7, ch = (off >> 4) & 7;
      int gch = ch ^ (row & 7);
      gll16((const char*)Kp +
                (((size_t)b * 2048 + kt * 64 + row) * 1024 + h * 64) * 2 + gch * 16,
            kv + off);
      gll16((const char*)Vt +
                ((size_t)(h * 64 + row) * 4096 + (size_t)b * 2048 + kt * 64) * 2 +
                gch * 16,
            kv + 8192 + off);
    }
    __syncthreads();  // staging drained

    // QK (mt-major, st transient) -> exp2 -> packed bf16 pairs in registers
    unsigned pk[4][2][2];  // [mt][nt][word]: w0 = keys gs*4+{0,1}, w1 = +{2,3}
    __builtin_amdgcn_s_setprio(1);
#pragma unroll
    for (int mt = 0; mt < 4; ++mt) {
      f32x4 st0 = {}, st1 = {};
      int row = mt * 16 + li;
#pragma unroll
      for (int ks = 0; ks < 2; ++ks) {
        int gch = (4 * ks + g) ^ (row & 7);
        bf16x8 kf = ldfrag(kv + row * 128 + gch * 16);
        st0 = mfma16(kf, qf[0][ks], st0);
        st1 = mfma16(kf, qf[1][ks], st1);
      }
      float p0 = __builtin_amdgcn_exp2f(st0[0]);
      float p1 = __builtin_amdgcn_exp2f(st0[1]);
      float p2 = __builtin_amdgcn_exp2f(st0[2]);
      float p3 = __builtin_amdgcn_exp2f(st0[3]);
      lsum[0] += (p0 + p1) + (p2 + p3);
      pk[mt][0][0] = cvtpk(p0, p1);
      pk[mt][0][1] = cvtpk(p2, p3);
      p0 = __builtin_amdgcn_exp2f(st1[0]);
      p1 = __builtin_amdgcn_exp2f(st1[1]);
      p2 = __builtin_amdgcn_exp2f(st1[2]);
      p3 = __builtin_amdgcn_exp2f(st1[3]);
      lsum[1] += (p0 + p1) + (p2 + p3);
      pk[mt][1][0] = cvtpk(p0, p1);
      pk[mt][1][1] = cvtpk(p2, p3);
    }
    __builtin_amdgcn_s_setprio(0);

    // in-register C-layout -> B-frag remap, then PV: acc += Vt_frag x P_frag
    __builtin_amdgcn_s_setprio(1);
#pragma unroll
    for (int kc = 0; kc < 2; ++kc) {
      unsigned a00 = pk[2 * kc][0][0], b00 = pk[2 * kc + 1][0][0];
      unsigned a01 = pk[2 * kc][0][1], b01 = pk[2 * kc + 1][0][1];
      unsigned a10 = pk[2 * kc][1][0], b10 = pk[2 * kc + 1][1][0];
      unsigned a11 = pk[2 * kc][1][1], b11 = pk[2 * kc + 1][1][1];
      swap32(a00, b00);
      swap16(a00, b00);
      swap32(a01, b01);
      swap16(a01, b01);
      swap32(a10, b10);
      swap16(a10, b10);
      swap32(a11, b11);
      swap16(a11, b11);
      uint4 u0 = {a00, a01, b00, b01};  // words 0..3: keys kc*32+g*8+{0..7}, q=li
      uint4 u1 = {a10, a11, b10, b11};
      bf16x8 pf0 = __builtin_bit_cast(bf16x8, u0);
      bf16x8 pf1 = __builtin_bit_cast(bf16x8, u1);
#pragma unroll
      for (int mtd = 0; mtd < 4; ++mtd) {
        int row = mtd * 16 + li;
        int gch = (4 * kc + g) ^ (row & 7);
        bf16x8 vf = ldfrag(kv + 8192 + row * 128 + gch * 16);
        acc[mtd][0] = mfma16(vf, pf0, acc[mtd][0]);
        acc[mtd][1] = mfma16(vf, pf1, acc[mtd][1]);
      }
    }
    __builtin_amdgcn_s_setprio(0);
  }

#pragma unroll
  for (int nt = 0; nt < 2; ++nt) {
    float l = lsum[nt];
    l += __shfl_xor(l, 16);
    l += __shfl_xor(l, 32);  // split-local denominator for q = nt*16+li
    float linv = 1.0f / l;
    size_t qrow = qrow0 + wv * 32 + nt * 16 + li;
    if (g == 0) pl[((size_t)sp * 4096 + qrow) * 16 + h] = l;
#pragma unroll
    for (int mtd = 0; mtd < 4; ++mtd) {
      bf16x4 o = {(__bf16)(acc[mtd][nt][0] * linv), (__bf16)(acc[mtd][nt][1] * linv),
                  (__bf16)(acc[mtd][nt][2] * linv), (__bf16)(acc[mtd][nt][3] * linv)};
      *(bf16x4*)(ctx + qrow * 1024 + h * 64 + mtd * 16 + g * 4) = o;
    }
  }
}

// combine splits: ctx = (c0*l0 + c1*l1 + c2*l2) / (l0+l1+l2); 8 elems/thread
__global__ __launch_bounds__(256) void combine_k(const __bf16* __restrict__ c0,
                                                 const __bf16* __restrict__ c1,
                                                 const __bf16* __restrict__ c2,
                                                 const float* __restrict__ pl,
                                                 __bf16* __restrict__ ctx) {
  size_t e = ((size_t)blockIdx.x * 256 + threadIdx.x) * 8;
  int qrow = (int)(e >> 10), h = ((int)e & 1023) >> 6;
  float l0 = pl[(size_t)qrow * 16 + h];
  float l1 = pl[(size_t)(4096 + qrow) * 16 + h];
  float l2 = pl[(size_t)(8192 + qrow) * 16 + h];
  float w = 1.0f / (l0 + l1 + l2);
  float w0 = l0 * w, w1 = l1 * w, w2 = l2 * w;
  bf16x8 a = *(const bf16x8*)(c0 + e);
  bf16x8 b = *(const bf16x8*)(c1 + e);
  bf16x8 c = *(const bf16x8*)(c2 + e);
  bf16x8 o;
#pragma unroll
  for (int i = 0; i < 8; ++i)
    o[i] = (__bf16)((float)a[i] * w0 + (float)b[i] * w1 + (float)c[i] * w2);
  *(bf16x8*)(ctx + e) = o;
}

// ---------------------------------------------------------------- launch
extern "C" void kernel_launch(void* const* d_in, const int* in_sizes, int n_in,
                              void* d_out, int out_size, void* d_ws, size_t ws_size,
                              hipStream_t stream) {
  const float* q = (const float*)d_in[0];
  const float* k = (const float*)d_in[1];
  const float* v = (const float*)d_in[2];
  const float* ind = (const float*)d_in[3];
  const float* Wq = (const float*)d_in[4];
  const float* Wk = (const float*)d_in[5];
  const float* Wv = (const float*)d_in[6];
  const float* Wo = (const float*)d_in[7];
  char* ws = (char*)d_ws;
  const size_t MB = 1024 * 1024;
  __bf16* WqT = (__bf16*)(ws + 24 * MB);
  __bf16* WkT = (__bf16*)(ws + 26 * MB);
  __bf16* WvT = (__bf16*)(ws + 28 * MB);
  __bf16* WoT = (__bf16*)(ws + 30 * MB);
  __bf16* Qp = (__bf16*)(ws + 32 * MB);
  __bf16* Kp = (__bf16*)(ws + 40 * MB);
  __bf16* Vtp = (__bf16*)(ws + 48 * MB);
  // 0-24 MB free for flash outputs; WqT/WkT/WvT dead after gemm_qkv
  __bf16* ctx0 = (__bf16*)(ws + 0);
  __bf16* ctx1 = (__bf16*)(ws + 8 * MB);
  __bf16* ctx2 = (__bf16*)(ws + 16 * MB);
  float* pl = (float*)(ws + 24 * MB);     // [3][4096][16] f32 = 768 KB (dead WqT)
  __bf16* ctx = (__bf16*)(ws + 48 * MB);  // over Vtp, dead once flash_k is done
  float* out = (float*)d_out;

  prep_k<<<dim3(4096), 256, 0, stream>>>(Wq, Wk, Wv, Wo, WqT, WkT, WvT, WoT);
  gemm_qkv<<<dim3(8, 32, 3), 256, 0, stream>>>(q, k, v, WqT, WkT, WvT, ind, Qp, Kp,
                                               Vtp);
  flash_k<<<dim3(1536), 256, 0, stream>>>(Qp, Kp, Vtp, ctx0, ctx1, ctx2, pl);
  combine_k<<<dim3(2048), 256, 0, stream>>>(ctx0, ctx1, ctx2, pl, ctx);
  gemm_out<<<dim3(16, 64), 256, 0, stream>>>(ctx, WoT, out);
}